// Round 3
// baseline (185.838 us; speedup 1.0000x reference)
//
#include <hip/hip_runtime.h>

#define BB   4
#define QS   512
#define KSZ  1024
#define DD   512
#define HH   128
#define DVV  512

#define SLABS 4
#define BKK  (KSZ / SLABS)   // 256 k per slab

__device__ __forceinline__ float rcp_fast(float x)  { return __builtin_amdgcn_rcpf(x); }
__device__ __forceinline__ float exp2_fast(float x) { return __builtin_amdgcn_exp2f(x); }

// ---------------------------------------------------------------------------
// Kernel A: fused projection + exp(2x).
// out[m][h] = exp2( 2*log2(e) * dot(A[m,:], W[:,h]) )
// Blocks [0, nq_blocks) do queries@W_q -> eq, the rest do keys@W_k -> ek.
// ---------------------------------------------------------------------------
__global__ __launch_bounds__(256) void proj_exp_kernel(
    const float* __restrict__ q,  const float* __restrict__ k,
    const float* __restrict__ Wq, const float* __restrict__ Wk,
    float* __restrict__ eq, float* __restrict__ ek, int nq_blocks)
{
    __shared__ float At[16][36];    // +4 pad
    __shared__ float Wt[32][128];

    const float* A; const float* W; float* outp; int m0;
    if ((int)blockIdx.x < nq_blocks) {
        A = q;  W = Wq; outp = eq; m0 = blockIdx.x * 16;
    } else {
        A = k;  W = Wk; outp = ek; m0 = (blockIdx.x - nq_blocks) * 16;
    }

    const int tid = threadIdx.x;
    const int h4  = tid & 31;
    const int r   = tid >> 5;

    float4 acc0 = {0.f,0.f,0.f,0.f};
    float4 acc1 = {0.f,0.f,0.f,0.f};

    for (int d0 = 0; d0 < DD; d0 += 32) {
        if (tid < 128) {
            int row = tid >> 3, c4 = tid & 7;
            *(float4*)&At[row][c4 * 4] =
                *(const float4*)&A[(size_t)(m0 + row) * DD + d0 + c4 * 4];
        }
        #pragma unroll
        for (int i = 0; i < 4; i++) {
            int f = tid + i * 256;
            int row = f >> 5, c4 = f & 31;
            *(float4*)&Wt[row][c4 * 4] =
                *(const float4*)&W[(size_t)(d0 + row) * HH + c4 * 4];
        }
        __syncthreads();
        #pragma unroll 4
        for (int kk = 0; kk < 32; kk++) {
            float4 w4 = *(const float4*)&Wt[kk][h4 * 4];
            float a0 = At[r][kk];
            float a1 = At[r + 8][kk];
            acc0.x = fmaf(a0, w4.x, acc0.x); acc0.y = fmaf(a0, w4.y, acc0.y);
            acc0.z = fmaf(a0, w4.z, acc0.z); acc0.w = fmaf(a0, w4.w, acc0.w);
            acc1.x = fmaf(a1, w4.x, acc1.x); acc1.y = fmaf(a1, w4.y, acc1.y);
            acc1.z = fmaf(a1, w4.z, acc1.z); acc1.w = fmaf(a1, w4.w, acc1.w);
        }
        __syncthreads();
    }

    const float C2L = 2.8853900817779268f;  // 2*log2(e)
    float4 o0, o1;
    o0.x = exp2_fast(acc0.x * C2L); o0.y = exp2_fast(acc0.y * C2L);
    o0.z = exp2_fast(acc0.z * C2L); o0.w = exp2_fast(acc0.w * C2L);
    o1.x = exp2_fast(acc1.x * C2L); o1.y = exp2_fast(acc1.y * C2L);
    o1.z = exp2_fast(acc1.z * C2L); o1.w = exp2_fast(acc1.w * C2L);
    *(float4*)&outp[(size_t)(m0 + r)     * HH + h4 * 4] = o0;
    *(float4*)&outp[(size_t)(m0 + r + 8) * HH + h4 * 4] = o1;
}

// ---------------------------------------------------------------------------
// Kernel B: sc[b][q][k] = sum_h w_v[h] * rcp(eq[b,q,h]*ek[b,k,h] + 1)
// True scores = -2*sc + const (const dropped -- cancels in softmax; the -2
// is folded into the exp2 constant of pv_gemm_kernel).
// ---------------------------------------------------------------------------
__global__ __launch_bounds__(256) void scores_kernel(
    const float* __restrict__ eq, const float* __restrict__ ek,
    const float* __restrict__ wv, float* __restrict__ sc)
{
    __shared__ float eqs[64][68];
    __shared__ float eks[64][68];
    __shared__ float wvs[HH];

    const int tid = threadIdx.x;
    const int b  = blockIdx.z;
    const int q0 = blockIdx.y * 64;
    const int k0 = blockIdx.x * 64;

    const float* eqb = eq + ((size_t)b * QS  + q0) * HH;
    const float* ekb = ek + ((size_t)b * KSZ + k0) * HH;

    if (tid < 32) *(float4*)&wvs[tid * 4] = *(const float4*)&wv[tid * 4];

    const int tk = tid & 15;
    const int tq = tid >> 4;

    float acc[4][4] = {};

    for (int hc = 0; hc < HH; hc += 64) {
        __syncthreads();
        #pragma unroll
        for (int i = 0; i < 4; i++) {
            int f = tid + i * 256;
            int row = f >> 4, c4 = f & 15;
            *(float4*)&eqs[row][c4 * 4] =
                *(const float4*)&eqb[(size_t)row * HH + hc + c4 * 4];
            *(float4*)&eks[row][c4 * 4] =
                *(const float4*)&ekb[(size_t)row * HH + hc + c4 * 4];
        }
        __syncthreads();

        for (int h0 = 0; h0 < 64; h0 += 4) {
            float4 wv4 = *(const float4*)&wvs[hc + h0];
            float4 eq4[4], ek4[4];
            #pragma unroll
            for (int j = 0; j < 4; j++) {
                eq4[j] = *(const float4*)&eqs[tq + 16 * j][h0];
                ek4[j] = *(const float4*)&eks[tk + 16 * j][h0];
            }
            #pragma unroll
            for (int jq = 0; jq < 4; jq++) {
                #pragma unroll
                for (int jk = 0; jk < 4; jk++) {
                    acc[jq][jk] = fmaf(wv4.x, rcp_fast(fmaf(eq4[jq].x, ek4[jk].x, 1.0f)), acc[jq][jk]);
                    acc[jq][jk] = fmaf(wv4.y, rcp_fast(fmaf(eq4[jq].y, ek4[jk].y, 1.0f)), acc[jq][jk]);
                    acc[jq][jk] = fmaf(wv4.z, rcp_fast(fmaf(eq4[jq].z, ek4[jk].z, 1.0f)), acc[jq][jk]);
                    acc[jq][jk] = fmaf(wv4.w, rcp_fast(fmaf(eq4[jq].w, ek4[jk].w, 1.0f)), acc[jq][jk]);
                }
            }
        }
    }

    float* scb = sc + ((size_t)b * QS + q0) * KSZ + k0;
    #pragma unroll
    for (int jq = 0; jq < 4; jq++)
        #pragma unroll
        for (int jk = 0; jk < 4; jk++)
            scb[(size_t)(tq + 16 * jq) * KSZ + tk + 16 * jk] = acc[jq][jk];
}

// ---------------------------------------------------------------------------
// Kernel C: partial PV over one K-slab of 256.
// part[slab][b][m][n] = sum_{k in slab} exp(-2*sc[b,m,k]) * V[b,k,n]
// rsp[slab][b][m]     = sum_{k in slab} exp(-2*sc[b,m,k])
// 64x64 tile, BK=32, double-buffered LDS, 8 K-steps. A stored k-major with
// XOR-swizzled m-granule ((m>>2)^((k>>2)&3)) -> conflict-free scalar stores
// AND conflict-free 16B-aligned b128 fragment reads. K-split x4 gives 1024
// blocks (~3-4 blocks/CU) for latency hiding.
// ---------------------------------------------------------------------------
__global__ __launch_bounds__(256) void pv_gemm_kernel(
    const float* __restrict__ sc, const float* __restrict__ val,
    float* __restrict__ part, float* __restrict__ rsp)
{
    __shared__ float As[2][32][68];
    __shared__ float Bs[2][32][68];
    __shared__ float rsum[64];

    const int tid  = threadIdx.x;
    const int b    = blockIdx.z >> 2;
    const int slab = blockIdx.z & 3;
    const int m0   = blockIdx.y * 64;
    const int n0   = blockIdx.x * 64;
    const int kb   = slab * BKK;

    const float* scb = sc  + ((size_t)b * QS + m0) * KSZ + kb;
    const float* vb  = val + (size_t)b * KSZ * DVV + (size_t)kb * DVV + n0;

    const int ar = tid >> 3;          // A rows ar, ar+32
    const int ak = (tid & 7) * 4;     // k offset within BK (4-aligned)
    const int sA = (ak >> 2) & 3;     // store-side swizzle for k-rows ak..ak+3
    const int bk = tid >> 4;          // B k-rows bk, bk+16
    const int bn = (tid & 15) * 4;

    // swizzled columns for m = ar and m = ar+32
    const int ca0 = 4 * ((ar >> 2)       ^ sA) + (ar & 3);
    const int ca1 = 4 * (((ar + 32) >> 2) ^ sA) + (ar & 3);

    const float CN = -2.8853900817779268f;  // -2*log2(e): exp(-2x)=2^(x*CN)

    float4 ea0, ea1, vv0, vv1;
    float rs0 = 0.f, rs1 = 0.f;

    // prefetch tile 0
    {
        float4 r0 = *(const float4*)&scb[(size_t)ar * KSZ + ak];
        float4 r1 = *(const float4*)&scb[(size_t)(ar + 32) * KSZ + ak];
        ea0.x = exp2_fast(r0.x * CN); ea0.y = exp2_fast(r0.y * CN);
        ea0.z = exp2_fast(r0.z * CN); ea0.w = exp2_fast(r0.w * CN);
        ea1.x = exp2_fast(r1.x * CN); ea1.y = exp2_fast(r1.y * CN);
        ea1.z = exp2_fast(r1.z * CN); ea1.w = exp2_fast(r1.w * CN);
        vv0 = *(const float4*)&vb[(size_t)bk * DVV + bn];
        vv1 = *(const float4*)&vb[(size_t)(bk + 16) * DVV + bn];
    }
    As[0][ak + 0][ca0] = ea0.x; As[0][ak + 1][ca0] = ea0.y;
    As[0][ak + 2][ca0] = ea0.z; As[0][ak + 3][ca0] = ea0.w;
    As[0][ak + 0][ca1] = ea1.x; As[0][ak + 1][ca1] = ea1.y;
    As[0][ak + 2][ca1] = ea1.z; As[0][ak + 3][ca1] = ea1.w;
    *(float4*)&Bs[0][bk][bn]      = vv0;
    *(float4*)&Bs[0][bk + 16][bn] = vv1;
    rs0 += ea0.x + ea0.y + ea0.z + ea0.w;
    rs1 += ea1.x + ea1.y + ea1.z + ea1.w;

    const int tm = (tid & 15) * 4;
    const int gm = tid & 15;          // tm>>2
    const int tn = (tid >> 4) * 4;
    float acc[4][4] = {};

    const int NSTEP = BKK / 32;       // 8
    for (int s = 0; s < NSTEP; s++) {
        __syncthreads();
        const int buf = s & 1;
        if (s < NSTEP - 1) {
            const int k0 = (s + 1) * 32;
            float4 r0 = *(const float4*)&scb[(size_t)ar * KSZ + k0 + ak];
            float4 r1 = *(const float4*)&scb[(size_t)(ar + 32) * KSZ + k0 + ak];
            ea0.x = exp2_fast(r0.x * CN); ea0.y = exp2_fast(r0.y * CN);
            ea0.z = exp2_fast(r0.z * CN); ea0.w = exp2_fast(r0.w * CN);
            ea1.x = exp2_fast(r1.x * CN); ea1.y = exp2_fast(r1.y * CN);
            ea1.z = exp2_fast(r1.z * CN); ea1.w = exp2_fast(r1.w * CN);
            vv0 = *(const float4*)&vb[(size_t)(k0 + bk) * DVV + bn];
            vv1 = *(const float4*)&vb[(size_t)(k0 + bk + 16) * DVV + bn];
        }
        #pragma unroll
        for (int kk = 0; kk < 32; kk++) {
            float4 a4 = *(const float4*)&As[buf][kk][4 * (gm ^ ((kk >> 2) & 3))];
            float4 b4 = *(const float4*)&Bs[buf][kk][tn];
            acc[0][0] = fmaf(a4.x, b4.x, acc[0][0]); acc[0][1] = fmaf(a4.x, b4.y, acc[0][1]);
            acc[0][2] = fmaf(a4.x, b4.z, acc[0][2]); acc[0][3] = fmaf(a4.x, b4.w, acc[0][3]);
            acc[1][0] = fmaf(a4.y, b4.x, acc[1][0]); acc[1][1] = fmaf(a4.y, b4.y, acc[1][1]);
            acc[1][2] = fmaf(a4.y, b4.z, acc[1][2]); acc[1][3] = fmaf(a4.y, b4.w, acc[1][3]);
            acc[2][0] = fmaf(a4.z, b4.x, acc[2][0]); acc[2][1] = fmaf(a4.z, b4.y, acc[2][1]);
            acc[2][2] = fmaf(a4.z, b4.z, acc[2][2]); acc[2][3] = fmaf(a4.z, b4.w, acc[2][3]);
            acc[3][0] = fmaf(a4.w, b4.x, acc[3][0]); acc[3][1] = fmaf(a4.w, b4.y, acc[3][1]);
            acc[3][2] = fmaf(a4.w, b4.z, acc[3][2]); acc[3][3] = fmaf(a4.w, b4.w, acc[3][3]);
        }
        if (s < NSTEP - 1) {
            const int nb = buf ^ 1;
            As[nb][ak + 0][ca0] = ea0.x; As[nb][ak + 1][ca0] = ea0.y;
            As[nb][ak + 2][ca0] = ea0.z; As[nb][ak + 3][ca0] = ea0.w;
            As[nb][ak + 0][ca1] = ea1.x; As[nb][ak + 1][ca1] = ea1.y;
            As[nb][ak + 2][ca1] = ea1.z; As[nb][ak + 3][ca1] = ea1.w;
            *(float4*)&Bs[nb][bk][bn]      = vv0;
            *(float4*)&Bs[nb][bk + 16][bn] = vv1;
            rs0 += ea0.x + ea0.y + ea0.z + ea0.w;
            rs1 += ea1.x + ea1.y + ea1.z + ea1.w;
        }
    }

    // partial row sums: rows ar/ar+32 loaded exclusively by 8 aligned lanes.
    #pragma unroll
    for (int m = 4; m; m >>= 1) {
        rs0 += __shfl_xor(rs0, m);
        rs1 += __shfl_xor(rs1, m);
    }
    if ((tid & 7) == 0) { rsum[ar] = rs0; rsum[ar + 32] = rs1; }
    __syncthreads();

    float* pb = part + (size_t)slab * BB * QS * DVV
                     + ((size_t)b * QS + m0) * DVV + n0;
    #pragma unroll
    for (int i = 0; i < 4; i++) {
        float4 o;
        o.x = acc[i][0]; o.y = acc[i][1]; o.z = acc[i][2]; o.w = acc[i][3];
        *(float4*)&pb[(size_t)(tm + i) * DVV + tn] = o;
    }
    if (tid < 64)
        rsp[slab * (BB * QS) + b * QS + m0 + tid] = rsum[tid];
}

// ---------------------------------------------------------------------------
// Kernel D: out = (sum_slab part[slab]) / (sum_slab rsp[slab]) per row.
// ---------------------------------------------------------------------------
__global__ __launch_bounds__(256) void reduce_kernel(
    const float* __restrict__ part, const float* __restrict__ rsp,
    float* __restrict__ outp)
{
    const int i = blockIdx.x * 256 + threadIdx.x;           // float4 index
    const size_t N4 = (size_t)BB * QS * DVV / 4;            // 262144
    const float4* p = (const float4*)part;
    float4 a = p[i], b = p[i + N4], c = p[i + 2 * N4], d = p[i + 3 * N4];
    const int bm = i >> 7;                                  // b*QS + m  (DVV/4=128)
    float rs = rsp[bm] + rsp[BB * QS + bm] + rsp[2 * BB * QS + bm] + rsp[3 * BB * QS + bm];
    float inv = rcp_fast(rs);
    float4 o;
    o.x = (a.x + b.x + c.x + d.x) * inv;
    o.y = (a.y + b.y + c.y + d.y) * inv;
    o.z = (a.z + b.z + c.z + d.z) * inv;
    o.w = (a.w + b.w + c.w + d.w) * inv;
    ((float4*)outp)[i] = o;
}

// ---------------------------------------------------------------------------
extern "C" void kernel_launch(void* const* d_in, const int* in_sizes, int n_in,
                              void* d_out, int out_size, void* d_ws, size_t ws_size,
                              hipStream_t stream)
{
    const float* queries = (const float*)d_in[0];
    const float* keys    = (const float*)d_in[1];
    const float* values  = (const float*)d_in[2];
    const float* Wq      = (const float*)d_in[3];
    const float* Wk      = (const float*)d_in[4];
    const float* wv      = (const float*)d_in[5];
    float* out = (float*)d_out;

    // ws (floats): eq 262144 | ek 524288 | sc 2097152 | part 4x1048576 | rsp 8192
    float* eq   = (float*)d_ws;
    float* ek   = eq + (size_t)BB * QS * HH;
    float* sc   = ek + (size_t)BB * KSZ * HH;
    float* part = sc + (size_t)BB * QS * KSZ;
    float* rsp  = part + (size_t)SLABS * BB * QS * DVV;

    const int nq_blocks = BB * QS / 16;   // 128
    const int nk_blocks = BB * KSZ / 16;  // 256
    proj_exp_kernel<<<dim3(nq_blocks + nk_blocks), 256, 0, stream>>>(
        queries, keys, Wq, Wk, eq, ek, nq_blocks);

    scores_kernel<<<dim3(KSZ / 64, QS / 64, BB), 256, 0, stream>>>(eq, ek, wv, sc);

    pv_gemm_kernel<<<dim3(DVV / 64, QS / 64, BB * SLABS), 256, 0, stream>>>(
        sc, values, part, rsp);

    reduce_kernel<<<dim3(BB * QS * DVV / 4 / 256), 256, 0, stream>>>(part, rsp, out);
}

// Round 4
// 165.815 us; speedup vs baseline: 1.1208x; 1.1208x over previous
//
#include <hip/hip_runtime.h>

#define BB   4
#define QS   512
#define KSZ  1024
#define DD   512
#define HH   128
#define DVV  512

typedef unsigned int uint;
typedef unsigned short ushort;
typedef __attribute__((ext_vector_type(8)))  short short8;   // 8 bf16 (4 VGPRs)
typedef __attribute__((ext_vector_type(16))) float f32x16;   // MFMA 32x32 acc

__device__ __forceinline__ float rcp_fast(float x)  { return __builtin_amdgcn_rcpf(x); }
__device__ __forceinline__ float exp2_fast(float x) { return __builtin_amdgcn_exp2f(x); }

// split fp32 -> bf16 hi (truncate) + bf16 lo (residual); exact to ~2^-17 rel
__device__ __forceinline__ void split1(float v, short& h, short& l) {
    uint u = __float_as_uint(v);
    h = (short)(u >> 16);
    float r = v - __uint_as_float(u & 0xffff0000u);
    l = (short)(__float_as_uint(r) >> 16);
}

// ---------------------------------------------------------------------------
// Kernel A: fused projection + exp(2x).
// out[m][h] = exp2( 2*log2(e) * dot(A[m,:], W[:,h]) )
// ---------------------------------------------------------------------------
__global__ __launch_bounds__(256) void proj_exp_kernel(
    const float* __restrict__ q,  const float* __restrict__ k,
    const float* __restrict__ Wq, const float* __restrict__ Wk,
    float* __restrict__ eq, float* __restrict__ ek, int nq_blocks)
{
    __shared__ float At[16][36];
    __shared__ float Wt[32][128];

    const float* A; const float* W; float* outp; int m0;
    if ((int)blockIdx.x < nq_blocks) {
        A = q;  W = Wq; outp = eq; m0 = blockIdx.x * 16;
    } else {
        A = k;  W = Wk; outp = ek; m0 = (blockIdx.x - nq_blocks) * 16;
    }

    const int tid = threadIdx.x;
    const int h4  = tid & 31;
    const int r   = tid >> 5;

    float4 acc0 = {0.f,0.f,0.f,0.f};
    float4 acc1 = {0.f,0.f,0.f,0.f};

    for (int d0 = 0; d0 < DD; d0 += 32) {
        if (tid < 128) {
            int row = tid >> 3, c4 = tid & 7;
            *(float4*)&At[row][c4 * 4] =
                *(const float4*)&A[(size_t)(m0 + row) * DD + d0 + c4 * 4];
        }
        #pragma unroll
        for (int i = 0; i < 4; i++) {
            int f = tid + i * 256;
            int row = f >> 5, c4 = f & 31;
            *(float4*)&Wt[row][c4 * 4] =
                *(const float4*)&W[(size_t)(d0 + row) * HH + c4 * 4];
        }
        __syncthreads();
        #pragma unroll 4
        for (int kk = 0; kk < 32; kk++) {
            float4 w4 = *(const float4*)&Wt[kk][h4 * 4];
            float a0 = At[r][kk];
            float a1 = At[r + 8][kk];
            acc0.x = fmaf(a0, w4.x, acc0.x); acc0.y = fmaf(a0, w4.y, acc0.y);
            acc0.z = fmaf(a0, w4.z, acc0.z); acc0.w = fmaf(a0, w4.w, acc0.w);
            acc1.x = fmaf(a1, w4.x, acc1.x); acc1.y = fmaf(a1, w4.y, acc1.y);
            acc1.z = fmaf(a1, w4.z, acc1.z); acc1.w = fmaf(a1, w4.w, acc1.w);
        }
        __syncthreads();
    }

    const float C2L = 2.8853900817779268f;  // 2*log2(e)
    float4 o0, o1;
    o0.x = exp2_fast(acc0.x * C2L); o0.y = exp2_fast(acc0.y * C2L);
    o0.z = exp2_fast(acc0.z * C2L); o0.w = exp2_fast(acc0.w * C2L);
    o1.x = exp2_fast(acc1.x * C2L); o1.y = exp2_fast(acc1.y * C2L);
    o1.z = exp2_fast(acc1.z * C2L); o1.w = exp2_fast(acc1.w * C2L);
    *(float4*)&outp[(size_t)(m0 + r)     * HH + h4 * 4] = o0;
    *(float4*)&outp[(size_t)(m0 + r + 8) * HH + h4 * 4] = o1;
}

// ---------------------------------------------------------------------------
// Kernel VT: V [b][k][n] fp32 -> vt_hi/vt_lo [b][n][k] bf16 (split).
// 32x32 LDS tile transpose; runs once, ~32 MB traffic.
// ---------------------------------------------------------------------------
__global__ __launch_bounds__(256) void vt_kernel(
    const float* __restrict__ val, ushort* __restrict__ vhi, ushort* __restrict__ vlo)
{
    __shared__ float Ts[32][33];
    const int b  = blockIdx.z;
    const int k0 = blockIdx.x * 32;
    const int n0 = blockIdx.y * 32;
    const int tid = threadIdx.x;

    {   // load 32k x 32n, coalesced along n
        const int kk = tid >> 3, n4 = (tid & 7) * 4;
        float4 v = *(const float4*)&val[((size_t)b * KSZ + k0 + kk) * DVV + n0 + n4];
        Ts[kk][n4 + 0] = v.x; Ts[kk][n4 + 1] = v.y;
        Ts[kk][n4 + 2] = v.z; Ts[kk][n4 + 3] = v.w;
    }
    __syncthreads();
    {   // read transposed, split, store 4 k-contiguous bf16 per thread
        const int nn = tid >> 3, k4 = (tid & 7) * 4;
        ushort h[4], l[4];
        #pragma unroll
        for (int i = 0; i < 4; i++) {
            short hh, ll;
            split1(Ts[k4 + i][nn], hh, ll);
            h[i] = (ushort)hh; l[i] = (ushort)ll;
        }
        size_t o = ((size_t)b * DVV + n0 + nn) * KSZ + k0 + k4;
        *(ushort4*)&vhi[o] = make_ushort4(h[0], h[1], h[2], h[3]);
        *(ushort4*)&vlo[o] = make_ushort4(l[0], l[1], l[2], l[3]);
    }
}

// ---------------------------------------------------------------------------
// Kernel B: P[b][q][k] = exp(-2 * sum_h w_v[h] * rcp(eq*ek + 1))   (fp32)
// plus per-64-k-tile row-sum partials rsp[b][q][16].
// (constant sum(w_v) dropped -- cancels in softmax)
// ---------------------------------------------------------------------------
__global__ __launch_bounds__(256) void scores_kernel(
    const float* __restrict__ eq, const float* __restrict__ ek,
    const float* __restrict__ wv, float* __restrict__ P, float* __restrict__ rsp)
{
    __shared__ float eqs[64][68];
    __shared__ float eks[64][68];
    __shared__ float wvs[HH];

    const int tid = threadIdx.x;
    const int b  = blockIdx.z;
    const int q0 = blockIdx.y * 64;
    const int k0 = blockIdx.x * 64;

    const float* eqb = eq + ((size_t)b * QS  + q0) * HH;
    const float* ekb = ek + ((size_t)b * KSZ + k0) * HH;

    if (tid < 32) *(float4*)&wvs[tid * 4] = *(const float4*)&wv[tid * 4];

    const int tk = tid & 15;
    const int tq = tid >> 4;

    float acc[4][4] = {};

    for (int hc = 0; hc < HH; hc += 64) {
        __syncthreads();
        #pragma unroll
        for (int i = 0; i < 4; i++) {
            int f = tid + i * 256;
            int row = f >> 4, c4 = f & 15;
            *(float4*)&eqs[row][c4 * 4] =
                *(const float4*)&eqb[(size_t)row * HH + hc + c4 * 4];
            *(float4*)&eks[row][c4 * 4] =
                *(const float4*)&ekb[(size_t)row * HH + hc + c4 * 4];
        }
        __syncthreads();

        for (int h0 = 0; h0 < 64; h0 += 4) {
            float4 wv4 = *(const float4*)&wvs[hc + h0];
            float4 eq4[4], ek4[4];
            #pragma unroll
            for (int j = 0; j < 4; j++) {
                eq4[j] = *(const float4*)&eqs[tq + 16 * j][h0];
                ek4[j] = *(const float4*)&eks[tk + 16 * j][h0];
            }
            #pragma unroll
            for (int jq = 0; jq < 4; jq++) {
                #pragma unroll
                for (int jk = 0; jk < 4; jk++) {
                    acc[jq][jk] = fmaf(wv4.x, rcp_fast(fmaf(eq4[jq].x, ek4[jk].x, 1.0f)), acc[jq][jk]);
                    acc[jq][jk] = fmaf(wv4.y, rcp_fast(fmaf(eq4[jq].y, ek4[jk].y, 1.0f)), acc[jq][jk]);
                    acc[jq][jk] = fmaf(wv4.z, rcp_fast(fmaf(eq4[jq].z, ek4[jk].z, 1.0f)), acc[jq][jk]);
                    acc[jq][jk] = fmaf(wv4.w, rcp_fast(fmaf(eq4[jq].w, ek4[jk].w, 1.0f)), acc[jq][jk]);
                }
            }
        }
    }

    const float CN = -2.8853900817779268f;  // -2*log2(e)
    float* pb = P + ((size_t)b * QS + q0) * KSZ + k0;
    #pragma unroll
    for (int jq = 0; jq < 4; jq++) {
        float rowp = 0.f;
        #pragma unroll
        for (int jk = 0; jk < 4; jk++) {
            float pv_ = exp2_fast(acc[jq][jk] * CN);
            pb[(size_t)(tq + 16 * jq) * KSZ + tk + 16 * jk] = pv_;
            rowp += pv_;
        }
        // reduce across the 16 k-threads (lane&15 groups)
        #pragma unroll
        for (int m = 8; m; m >>= 1) rowp += __shfl_xor(rowp, m);
        if ((tid & 15) == 0)
            rsp[((size_t)b * QS + q0 + tq + 16 * jq) * 16 + blockIdx.x] = rowp;
    }
}

// ---------------------------------------------------------------------------
// Kernel C: out = P @ V / rowsum via MFMA (split-bf16, 3 MFMAs per k16).
// No LDS staging, no inner barriers: A-frags straight from P (fp32->bf16 split
// in regs), B-frags straight from pre-transposed vt_hi/vt_lo. Block = 64x64
// (4 waves of 32x32). XCD swizzle: id&7 groups all 8 n-tiles of 4 (b,m)-groups
// per XCD for L2 locality (~3 MB slab < 4 MB L2/XCD).
// ---------------------------------------------------------------------------
__global__ __launch_bounds__(256) void pv_mfma_kernel(
    const float* __restrict__ P, const ushort* __restrict__ vhi,
    const ushort* __restrict__ vlo, const float* __restrict__ rsp,
    float* __restrict__ outp)
{
    __shared__ float invs[64];

    const int id = blockIdx.x;          // 256 blocks
    const int x  = id & 7;              // ~XCD
    const int j  = id >> 3;             // 0..31
    const int bm = x * 4 + (j >> 3);    // 0..31 : (b, m-tile) group
    const int nt = j & 7;               // n-tile 0..7
    const int b  = bm >> 3, mt = bm & 7;

    const int tid = threadIdx.x, w = tid >> 6, lane = tid & 63;

    if (tid < 64) {
        const float* rp = rsp + ((size_t)b * QS + mt * 64 + tid) * 16;
        float s = 0.f;
        #pragma unroll
        for (int i = 0; i < 16; i++) s += rp[i];
        invs[tid] = rcp_fast(s);
    }
    __syncthreads();

    const int mw = mt * 64 + (w & 1) * 32;
    const int nw = nt * 64 + (w >> 1) * 32;
    const int row = lane & 31, kg = lane >> 5;

    const float*  pa = P   + ((size_t)b * QS  + mw + row) * KSZ;
    const ushort* bh = vhi + ((size_t)b * DVV + nw + row) * KSZ;
    const ushort* bl = vlo + ((size_t)b * DVV + nw + row) * KSZ;

    f32x16 acc;
    #pragma unroll
    for (int i = 0; i < 16; i++) acc[i] = 0.f;

    #pragma unroll 4
    for (int kb = 0; kb < KSZ; kb += 16) {
        const int ka = kb + kg * 8;
        float4 p0 = *(const float4*)(pa + ka);
        float4 p1 = *(const float4*)(pa + ka + 4);
        short8 vh = *(const short8*)(bh + ka);
        short8 vl = *(const short8*)(bl + ka);
        short8 ah, al;
        {
            float v[8] = {p0.x, p0.y, p0.z, p0.w, p1.x, p1.y, p1.z, p1.w};
            #pragma unroll
            for (int i = 0; i < 8; i++) {
                short hh, ll; split1(v[i], hh, ll);
                ah[i] = hh; al[i] = ll;
            }
        }
        acc = __builtin_amdgcn_mfma_f32_32x32x16_bf16(ah, vh, acc, 0, 0, 0);
        acc = __builtin_amdgcn_mfma_f32_32x32x16_bf16(ah, vl, acc, 0, 0, 0);
        acc = __builtin_amdgcn_mfma_f32_32x32x16_bf16(al, vh, acc, 0, 0, 0);
    }

    // C/D layout (m74/m101-verified): col = lane&31, row = (reg&3)+8*(reg>>2)+4*(lane>>5)
    float* ob = outp + ((size_t)b * QS + mt * 64) * DVV + nt * 64 + (w >> 1) * 32;
    const int col = lane & 31;
    #pragma unroll
    for (int r = 0; r < 16; r++) {
        const int rb = (w & 1) * 32 + (r & 3) + 8 * (r >> 2) + 4 * kg;
        ob[(size_t)rb * DVV + col] = acc[r] * invs[rb];
    }
}

// ---------------------------------------------------------------------------
extern "C" void kernel_launch(void* const* d_in, const int* in_sizes, int n_in,
                              void* d_out, int out_size, void* d_ws, size_t ws_size,
                              hipStream_t stream)
{
    const float* queries = (const float*)d_in[0];
    const float* keys    = (const float*)d_in[1];
    const float* values  = (const float*)d_in[2];
    const float* Wq      = (const float*)d_in[3];
    const float* Wk      = (const float*)d_in[4];
    const float* wv      = (const float*)d_in[5];
    float* out = (float*)d_out;

    // ws (floats): eq 262144 | ek 524288 | P 2097152 | rsp 32768 | vt_hi | vt_lo
    float* eq  = (float*)d_ws;
    float* ek  = eq  + (size_t)BB * QS * HH;
    float* P   = ek  + (size_t)BB * KSZ * HH;
    float* rsp = P   + (size_t)BB * QS * KSZ;
    ushort* vhi = (ushort*)(rsp + (size_t)BB * QS * 16);
    ushort* vlo = vhi + (size_t)BB * KSZ * DVV;

    vt_kernel<<<dim3(KSZ / 32, DVV / 32, BB), 256, 0, stream>>>(values, vhi, vlo);

    const int nq_blocks = BB * QS / 16;   // 128
    const int nk_blocks = BB * KSZ / 16;  // 256
    proj_exp_kernel<<<dim3(nq_blocks + nk_blocks), 256, 0, stream>>>(
        queries, keys, Wq, Wk, eq, ek, nq_blocks);

    scores_kernel<<<dim3(KSZ / 64, QS / 64, BB), 256, 0, stream>>>(eq, ek, wv, P, rsp);

    pv_mfma_kernel<<<dim3(256), 256, 0, stream>>>(P, vhi, vlo, rsp, out);
}